// Round 9
// baseline (447.538 us; speedup 1.0000x reference)
//
#include <hip/hip_runtime.h>

typedef unsigned short u16;
typedef unsigned int u32;
typedef __bf16 bf16x8 __attribute__((ext_vector_type(8)));
typedef float floatx4 __attribute__((ext_vector_type(4)));
typedef u16 u16x4 __attribute__((ext_vector_type(4)));
typedef u16 u16x8 __attribute__((ext_vector_type(8)));
typedef u32 u32x2 __attribute__((ext_vector_type(2)));

#define B_ 4
#define T_ 1024
#define C_ 2048
#define H_ 32
#define HD_ 64

__device__ __forceinline__ float b2f(u16 u) {
    u32 x = ((u32)u) << 16;
    return __builtin_bit_cast(float, x);
}
__device__ __forceinline__ u16 f2b(float f) {          // RNE (epilogues)
    u32 i = __builtin_bit_cast(u32, f);
    u32 r = (i + 0x7FFFu + ((i >> 16) & 1u)) >> 16;
    return (u16)r;
}
// pack two fp32 -> two bf16 (round-half-up), 2 adds + 1 v_perm_b32
__device__ __forceinline__ u32 pack2(float a, float b) {
    const u32 ua = __builtin_bit_cast(u32, a) + 0x8000u;
    const u32 ub = __builtin_bit_cast(u32, b) + 0x8000u;
    return __builtin_amdgcn_perm(ub, ua, 0x07060302u);  // [ub_hi : ua_hi]
}

#define GLOAD16(gp, lp) __builtin_amdgcn_global_load_lds( \
    (const __attribute__((address_space(1))) void*)(gp),  \
    (__attribute__((address_space(3))) void*)(lp), 16, 0, 0)

// ---------------------------------------------------------------------------
// fused fp32 -> bf16 convert for x | Wqkv_w | out_w (contiguous dst in ws).
// Verified round 4 (gemm counters unchanged; -2 launches).
// ---------------------------------------------------------------------------
__global__ __launch_bounds__(256) void convert_all(const float* __restrict__ x,
                                                   const float* __restrict__ wqkv,
                                                   const float* __restrict__ outw,
                                                   u16* __restrict__ dst) {
    const int stride = gridDim.x * 256;
    for (int i = blockIdx.x * 256 + threadIdx.x; i < 6291456; i += stride) {
        const float* s;
        int off;
        if (i < 2097152) { s = x; off = i; }
        else if (i < 5242880) { s = wqkv; off = i - 2097152; }
        else { s = outw; off = i - 5242880; }
        const floatx4 v = *(const floatx4*)(s + (size_t)off * 4);
        const u32x2 h = {pack2(v.x, v.y), pack2(v.z, v.w)};
        *(u32x2*)(dst + (size_t)i * 4) = h;
    }
}

// ---------------------------------------------------------------------------
// GEMM: C[m,n] = sum_k A[m,k] * W[n,k] + bias[n]   (A, W bf16 row-major)
// m97 structure + XOR-swizzled LDS. Verified 828 TF on the QKV shape.
// (256^2 8-phase measured SLOWER at this shape: 384 blocks at 1 block/CU ->
// 75% tail cap, resident MfmaUtil no better than 37%. Do not revisit.)
// MODE 0: epilogue bias + RoPE + scatter to q/k/v (B,H,T,hd) bf16.
// MODE 1: epilogue bias, fp32 row-major store.
// ---------------------------------------------------------------------------
template <int MODE>
__global__ __launch_bounds__(256) void gemm_bt(const u16* __restrict__ A,
                                               const u16* __restrict__ W,
                                               const float* __restrict__ bias,
                                               const float* __restrict__ rope,
                                               void* __restrict__ o0v,
                                               u16* __restrict__ o1,
                                               u16* __restrict__ o2) {
    const int Kdim = 2048;
    __shared__ __align__(16) u16 As[128 * 64];
    __shared__ __align__(16) u16 Bs[128 * 64];

    const int tid = threadIdx.x;
    const int w = tid >> 6, lane = tid & 63;
    const int wr = w >> 1, wc = w & 1;
    const int quad = lane >> 4, l15 = lane & 15;
    const int mBase = blockIdx.y * 128, nBase = blockIdx.x * 128;

    floatx4 acc[4][4] = {};

    // swizzled staging: local row lrow, fetch col-block (lane&7)^lrow
    const int lrow = lane >> 3;
    const int lcol = ((lane & 7) ^ lrow) * 8;
    const u16* Ap = A + (size_t)(mBase + lrow) * Kdim + lcol;
    const u16* Wp = W + (size_t)(nBase + lrow) * Kdim + lcol;

    const int xk = l15 & 7;   // read-side XOR key (row & 7)

    for (int k0 = 0; k0 < Kdim; k0 += 64) {
#pragma unroll
        for (int i = 0; i < 4; i++) {
            const int c = i * 4 + w;
            GLOAD16(Ap + (size_t)c * 8 * Kdim + k0, &As[c * 512]);
            GLOAD16(Wp + (size_t)c * 8 * Kdim + k0, &Bs[c * 512]);
        }
        __syncthreads();
#pragma unroll
        for (int ks = 0; ks < 64; ks += 32) {
            bf16x8 af[4], bfr[4];
#pragma unroll
            for (int i = 0; i < 4; i++) {
                const int co = (((ks >> 3) + quad) ^ xk) * 8;
                af[i] = *(const bf16x8*)&As[(wr * 64 + i * 16 + l15) * 64 + co];
            }
#pragma unroll
            for (int j = 0; j < 4; j++) {
                const int co = (((ks >> 3) + quad) ^ xk) * 8;
                bfr[j] = *(const bf16x8*)&Bs[(wc * 64 + j * 16 + l15) * 64 + co];
            }
#pragma unroll
            for (int i = 0; i < 4; i++)
#pragma unroll
                for (int j = 0; j < 4; j++)
                    acc[i][j] = __builtin_amdgcn_mfma_f32_16x16x32_bf16(af[i], bfr[j], acc[i][j], 0, 0, 0);
        }
        __syncthreads();
    }

    // epilogue: C/D layout col = lane&15 (per j-frag), row = quad*4 + reg (per i-frag)
    const int nq = nBase + wc * 64;
    float bv[4];
#pragma unroll
    for (int j = 0; j < 4; j++) bv[j] = bias[nq + j * 16 + l15];

    if (MODE == 0) {
        const int region = nq >> 11;            // 0=q 1=k 2=v (tile never straddles)
        const int h = (nq & 2047) >> 6;
        const int d = l15;
        u16* dst = (region == 0) ? (u16*)o0v : ((region == 1) ? o1 : o2);
#pragma unroll
        for (int i = 0; i < 4; i++) {
#pragma unroll
            for (int r = 0; r < 4; r++) {
                const int m = mBase + wr * 64 + i * 16 + quad * 4 + r;
                const int b = m >> 10, t = m & 1023;
                float v0 = acc[i][0][r] + bv[0];
                float v1 = acc[i][1][r] + bv[1];
                float v2 = acc[i][2][r] + bv[2];
                float v3 = acc[i][3][r] + bv[3];
                const size_t base = ((size_t)(b * H_ + h) * T_ + t) * HD_;
                if (region < 2) {
                    const float cz = rope[t * 32 + d * 2];
                    const float sz = rope[t * 32 + d * 2 + 1];
                    const float n0 = v0 * cz - v1 * sz;
                    const float n1 = v1 * cz + v0 * sz;
                    dst[base + d] = f2b(n0);
                    dst[base + 16 + d] = f2b(n1);
                } else {
                    dst[base + d] = f2b(v0);
                    dst[base + 16 + d] = f2b(v1);
                }
                dst[base + 32 + d] = f2b(v2);
                dst[base + 48 + d] = f2b(v3);
            }
        }
    } else {
        float* outf = (float*)o0v;
#pragma unroll
        for (int i = 0; i < 4; i++)
#pragma unroll
            for (int r = 0; r < 4; r++) {
                const int m = mBase + wr * 64 + i * 16 + quad * 4 + r;
                const size_t o = (size_t)m * 2048 + nq;
#pragma unroll
                for (int j = 0; j < 4; j++)
                    outf[o + j * 16 + l15] = acc[i][j][r] + bv[j];
            }
    }
}

// ---------------------------------------------------------------------------
// MFMA flash attention — WAVE-DECOUPLED rewrite (round 9).
// Diagnosis across rounds 0-8: latency-bound with convoy amplification. The
// per-iteration __syncthreads existed ONLY for the cooperatively-staged Vt
// LDS buffer; it forced all 4 waves to serialize on the slowest wave's
// memory stalls, 17x per block (MfmaUtil ~5%, VALUBusy ~21%).
// This version: each wave (16 q-rows) is fully independent —
//  * V^T fragments loaded directly to registers (64 scalar u16/lane/tile;
//    mapping V[key=quad*8+j][hd=mi*16+l15], identical to what the verified
//    Vt ds_read path delivered). Vt LDS + ALL barriers deleted. V global
//    traffic x4, but from L2 (~6 us amortized) — we run at 12% HBM.
//  * Pt stays (per-wave buffer, lgkm-ordered within the wave, no barrier
//    needed — same as all verified rounds).
//  * K-prefetch kC[8] single-buffer WAR (round-7, proven). T13 defer-max
//    (round-6, proven). No setprio (round-8 suspect). No launch-bounds pin
//    (round-5 spill lesson); vf overlaps dead st — peak VGPR ~110-120.
// Tripwire: attn VGPR small + WRITE_SIZE >> 16 MB => spill; dur worse =>
// VMEM-issue/L2 pressure — revert to round-7 structure either way.
// ---------------------------------------------------------------------------
#define VT_STR 72

#define LOADK(DST, KT)                                                         \
  {                                                                            \
    const u16* kp_ = kbase + (size_t)(KT) * 64 * HD_;                          \
    _Pragma("unroll") for (int mi = 0; mi < 4; mi++) {                         \
      const u16* kr_ = kp_ + (mi * 16 + l15) * HD_ + quad * 8;                 \
      DST[2 * mi]     = __builtin_bit_cast(bf16x8, *(const u16x8*)(kr_));      \
      DST[2 * mi + 1] = __builtin_bit_cast(bf16x8, *(const u16x8*)(kr_ + 32)); \
    }                                                                          \
  }

__global__ __launch_bounds__(256) void attn_mfma(const u16* __restrict__ qT,
                                                 const u16* __restrict__ kT,
                                                 const u16* __restrict__ vT,
                                                 u16* __restrict__ ctx) {
    __shared__ __align__(16) u16 Pt[4 * 16 * VT_STR];    // per-wave P^T: [q][key]

    const int tid = threadIdx.x;
    const int w = tid >> 6, lane = tid & 63;
    const int quad = lane >> 4, l15 = lane & 15;
    const int bh = blockIdx.y;
    const size_t headBase = (size_t)bh * (T_ * HD_);

    u16* myPt = &Pt[w * 16 * VT_STR];
    const float SC = 0.18033688011112042f;   // 0.125 * log2(e)
    const u16* kbase = kT + headBase;
    const u16* vbase = vT + headBase;

#pragma unroll 1
    for (int ti = 0; ti < 2; ti++) {
        const int qt = ti ? (15 - (int)blockIdx.x) : (int)blockIdx.x;
        const int qrow = w * 16 + l15;

        bf16x8 qf[2];
        {
            const u16* qr = qT + headBase + ((size_t)qt * 64 + qrow) * HD_ + quad * 8;
            qf[0] = __builtin_bit_cast(bf16x8, *(const u16x8*)(qr));
            qf[1] = __builtin_bit_cast(bf16x8, *(const u16x8*)(qr + 32));
        }

        float m_i = -1e30f, l_i = 0.f;
        floatx4 oacc[4] = {};

        bf16x8 kC[8];
        LOADK(kC, 0)

#pragma unroll 1
        for (int kt = 0; kt <= qt; kt++) {
            floatx4 st[4] = {};
#pragma unroll
            for (int mi = 0; mi < 4; mi++) {
                st[mi] = __builtin_amdgcn_mfma_f32_16x16x32_bf16(kC[2 * mi], qf[0], st[mi], 0, 0, 0);
                st[mi] = __builtin_amdgcn_mfma_f32_16x16x32_bf16(kC[2 * mi + 1], qf[1], st[mi], 0, 0, 0);
            }

            // prefetch next K tile into the SAME registers (WAR after MFMA reads)
            if (kt < qt) LOADK(kC, kt + 1)

            float pmax = -1e30f;
#pragma unroll
            for (int mi = 0; mi < 4; mi++)
#pragma unroll
                for (int r = 0; r < 4; r++) {
                    float sv = st[mi][r] * SC;   // score in log2 domain
                    if (kt == qt && (mi * 16 + quad * 4 + r) > qrow) sv = -1e30f;
                    st[mi][r] = sv;
                    pmax = fmaxf(pmax, sv);
                }
            pmax = fmaxf(pmax, __shfl_xor(pmax, 16, 64));
            pmax = fmaxf(pmax, __shfl_xor(pmax, 32, 64));

            // T13 defer-max: skip rescale chain unless max grew by >11 (log2)
            if (!__all(pmax <= m_i + 11.0f)) {
                const float mnew = fmaxf(m_i, pmax);
                const float alpha = __builtin_amdgcn_exp2f(m_i - mnew);
                m_i = mnew;
                l_i *= alpha;
#pragma unroll
                for (int mi = 0; mi < 4; mi++) oacc[mi] *= alpha;
            }

            float psum = 0.f;
#pragma unroll
            for (int mi = 0; mi < 4; mi++) {
                float p[4];
#pragma unroll
                for (int r = 0; r < 4; r++) {
                    p[r] = __builtin_amdgcn_exp2f(st[mi][r] - m_i);
                    psum += p[r];
                }
                const u32x2 pk2 = {pack2(p[0], p[1]), pack2(p[2], p[3])};
                *(u32x2*)&myPt[l15 * VT_STR + mi * 16 + quad * 4] = pk2;
            }
            psum += __shfl_xor(psum, 16, 64);
            psum += __shfl_xor(psum, 32, 64);
            l_i += psum;

            // V^T fragments direct from global (st is dead; vf reuses its regs).
            // vf[mi][h][j] = V[key = h*32 + quad*8 + j][hd = mi*16 + l15]
            // == the exact element the old Vt ds_read delivered.
            bf16x8 vf[4][2];
            {
                const u16* vp = vbase + (size_t)kt * 64 * HD_ + l15;
#pragma unroll
                for (int mi = 0; mi < 4; mi++)
#pragma unroll
                    for (int h = 0; h < 2; h++) {
                        u16x8 tmp;
#pragma unroll
                        for (int j = 0; j < 8; j++)
                            tmp[j] = vp[(h * 32 + quad * 8 + j) * HD_ + mi * 16];
                        vf[mi][h] = __builtin_bit_cast(bf16x8, tmp);
                    }
            }

            bf16x8 pf[2];
            pf[0] = __builtin_bit_cast(bf16x8, *(const u16x8*)&myPt[l15 * VT_STR + quad * 8]);
            pf[1] = __builtin_bit_cast(bf16x8, *(const u16x8*)&myPt[l15 * VT_STR + 32 + quad * 8]);
#pragma unroll
            for (int mi = 0; mi < 4; mi++) {
                oacc[mi] = __builtin_amdgcn_mfma_f32_16x16x32_bf16(vf[mi][0], pf[0], oacc[mi], 0, 0, 0);
                oacc[mi] = __builtin_amdgcn_mfma_f32_16x16x32_bf16(vf[mi][1], pf[1], oacc[mi], 0, 0, 0);
            }
        }

        const float inv = 1.0f / l_i;
        const int b = bh >> 5, h = bh & 31;
        const int t = qt * 64 + qrow;
        u16* cp = ctx + ((size_t)(b * T_ + t)) * C_ + h * HD_;
#pragma unroll
        for (int mi = 0; mi < 4; mi++) {
            const u16x4 ov = {f2b(oacc[mi][0] * inv), f2b(oacc[mi][1] * inv),
                              f2b(oacc[mi][2] * inv), f2b(oacc[mi][3] * inv)};
            *(u16x4*)(cp + mi * 16 + quad * 4) = ov;
        }
    }
}

extern "C" void kernel_launch(void* const* d_in, const int* in_sizes, int n_in,
                              void* d_out, int out_size, void* d_ws, size_t ws_size,
                              hipStream_t stream) {
    const float* x      = (const float*)d_in[0];
    const float* rope   = (const float*)d_in[3];
    const float* Wqkv_w = (const float*)d_in[4];
    const float* Wqkv_b = (const float*)d_in[5];
    const float* out_w  = (const float*)d_in[6];
    const float* out_b  = (const float*)d_in[7];
    float* out = (float*)d_out;

    // ws layout (u16 elems), total 100.7 MB:
    //   xb 8.39M | wqkvb 12.58M | outwb 4.19M | qT 8.39M | kT 8.39M | vT 8.39M
    //   xb|wqkvb|outwb contiguous (fused convert); ctx aliases xb (x dead after gemm0)
    const size_t headElems = (size_t)B_ * H_ * T_ * HD_;     // 8388608
    u16* xb    = (u16*)d_ws;
    u16* wqkvb = xb + headElems;
    u16* outwb = wqkvb + 12582912;
    u16* qTp   = outwb + 4194304;
    u16* kTp   = qTp + headElems;
    u16* vTp   = kTp + headElems;
    u16* ctx   = xb;

    convert_all<<<dim3(3072), 256, 0, stream>>>(x, Wqkv_w, out_w, xb);

    gemm_bt<0><<<dim3(48, 32), 256, 0, stream>>>(xb, wqkvb, Wqkv_b, rope, qTp, kTp, vTp);
    attn_mfma<<<dim3(8, 128), 256, 0, stream>>>(qTp, kTp, vTp, ctx);
    gemm_bt<1><<<dim3(16, 32), 256, 0, stream>>>(ctx, outwb, out_b, rope, out, nullptr, nullptr);
}

// Round 10
// 427.061 us; speedup vs baseline: 1.0479x; 1.0479x over previous
//
#include <hip/hip_runtime.h>

typedef unsigned short u16;
typedef unsigned int u32;
typedef __bf16 bf16x8 __attribute__((ext_vector_type(8)));
typedef float floatx4 __attribute__((ext_vector_type(4)));
typedef u16 u16x4 __attribute__((ext_vector_type(4)));
typedef u16 u16x8 __attribute__((ext_vector_type(8)));
typedef u32 u32x2 __attribute__((ext_vector_type(2)));

#define B_ 4
#define T_ 1024
#define C_ 2048
#define H_ 32
#define HD_ 64

__device__ __forceinline__ float b2f(u16 u) {
    u32 x = ((u32)u) << 16;
    return __builtin_bit_cast(float, x);
}
__device__ __forceinline__ u16 f2b(float f) {          // RNE (epilogues)
    u32 i = __builtin_bit_cast(u32, f);
    u32 r = (i + 0x7FFFu + ((i >> 16) & 1u)) >> 16;
    return (u16)r;
}
// pack two fp32 -> two bf16 (round-half-up), 2 adds + 1 v_perm_b32
__device__ __forceinline__ u32 pack2(float a, float b) {
    const u32 ua = __builtin_bit_cast(u32, a) + 0x8000u;
    const u32 ub = __builtin_bit_cast(u32, b) + 0x8000u;
    return __builtin_amdgcn_perm(ub, ua, 0x07060302u);  // [ub_hi : ua_hi]
}

#define GLOAD16(gp, lp) __builtin_amdgcn_global_load_lds( \
    (const __attribute__((address_space(1))) void*)(gp),  \
    (__attribute__((address_space(3))) void*)(lp), 16, 0, 0)

#define LGKM0() asm volatile("s_waitcnt lgkmcnt(0)" ::: "memory")

// ---------------------------------------------------------------------------
// fused fp32 -> bf16 convert for x | Wqkv_w | out_w (contiguous dst in ws).
// Verified round 4 (gemm counters unchanged; -2 launches).
// ---------------------------------------------------------------------------
__global__ __launch_bounds__(256) void convert_all(const float* __restrict__ x,
                                                   const float* __restrict__ wqkv,
                                                   const float* __restrict__ outw,
                                                   u16* __restrict__ dst) {
    const int stride = gridDim.x * 256;
    for (int i = blockIdx.x * 256 + threadIdx.x; i < 6291456; i += stride) {
        const float* s;
        int off;
        if (i < 2097152) { s = x; off = i; }
        else if (i < 5242880) { s = wqkv; off = i - 2097152; }
        else { s = outw; off = i - 5242880; }
        const floatx4 v = *(const floatx4*)(s + (size_t)off * 4);
        const u32x2 h = {pack2(v.x, v.y), pack2(v.z, v.w)};
        *(u32x2*)(dst + (size_t)i * 4) = h;
    }
}

// ---------------------------------------------------------------------------
// GEMM: C[m,n] = sum_k A[m,k] * W[n,k] + bias[n]   (A, W bf16 row-major)
// m97 structure + XOR-swizzled LDS. Verified 828 TF on the QKV shape.
// (256^2 8-phase measured SLOWER at this shape: 384 blocks at 1 block/CU ->
// 75% tail cap, resident MfmaUtil no better than 37%. Do not revisit.)
// MODE 0: epilogue bias + RoPE + scatter to q/k/v (B,H,T,hd) bf16.
// MODE 1: epilogue bias, fp32 row-major store.
// ---------------------------------------------------------------------------
template <int MODE>
__global__ __launch_bounds__(256) void gemm_bt(const u16* __restrict__ A,
                                               const u16* __restrict__ W,
                                               const float* __restrict__ bias,
                                               const float* __restrict__ rope,
                                               void* __restrict__ o0v,
                                               u16* __restrict__ o1,
                                               u16* __restrict__ o2) {
    const int Kdim = 2048;
    __shared__ __align__(16) u16 As[128 * 64];
    __shared__ __align__(16) u16 Bs[128 * 64];

    const int tid = threadIdx.x;
    const int w = tid >> 6, lane = tid & 63;
    const int wr = w >> 1, wc = w & 1;
    const int quad = lane >> 4, l15 = lane & 15;
    const int mBase = blockIdx.y * 128, nBase = blockIdx.x * 128;

    floatx4 acc[4][4] = {};

    // swizzled staging: local row lrow, fetch col-block (lane&7)^lrow
    const int lrow = lane >> 3;
    const int lcol = ((lane & 7) ^ lrow) * 8;
    const u16* Ap = A + (size_t)(mBase + lrow) * Kdim + lcol;
    const u16* Wp = W + (size_t)(nBase + lrow) * Kdim + lcol;

    const int xk = l15 & 7;   // read-side XOR key (row & 7)

    for (int k0 = 0; k0 < Kdim; k0 += 64) {
#pragma unroll
        for (int i = 0; i < 4; i++) {
            const int c = i * 4 + w;
            GLOAD16(Ap + (size_t)c * 8 * Kdim + k0, &As[c * 512]);
            GLOAD16(Wp + (size_t)c * 8 * Kdim + k0, &Bs[c * 512]);
        }
        __syncthreads();
#pragma unroll
        for (int ks = 0; ks < 64; ks += 32) {
            bf16x8 af[4], bfr[4];
#pragma unroll
            for (int i = 0; i < 4; i++) {
                const int co = (((ks >> 3) + quad) ^ xk) * 8;
                af[i] = *(const bf16x8*)&As[(wr * 64 + i * 16 + l15) * 64 + co];
            }
#pragma unroll
            for (int j = 0; j < 4; j++) {
                const int co = (((ks >> 3) + quad) ^ xk) * 8;
                bfr[j] = *(const bf16x8*)&Bs[(wc * 64 + j * 16 + l15) * 64 + co];
            }
#pragma unroll
            for (int i = 0; i < 4; i++)
#pragma unroll
                for (int j = 0; j < 4; j++)
                    acc[i][j] = __builtin_amdgcn_mfma_f32_16x16x32_bf16(af[i], bfr[j], acc[i][j], 0, 0, 0);
        }
        __syncthreads();
    }

    // epilogue: C/D layout col = lane&15 (per j-frag), row = quad*4 + reg (per i-frag)
    const int nq = nBase + wc * 64;
    float bv[4];
#pragma unroll
    for (int j = 0; j < 4; j++) bv[j] = bias[nq + j * 16 + l15];

    if (MODE == 0) {
        const int region = nq >> 11;            // 0=q 1=k 2=v (tile never straddles)
        const int h = (nq & 2047) >> 6;
        const int d = l15;
        u16* dst = (region == 0) ? (u16*)o0v : ((region == 1) ? o1 : o2);
#pragma unroll
        for (int i = 0; i < 4; i++) {
#pragma unroll
            for (int r = 0; r < 4; r++) {
                const int m = mBase + wr * 64 + i * 16 + quad * 4 + r;
                const int b = m >> 10, t = m & 1023;
                float v0 = acc[i][0][r] + bv[0];
                float v1 = acc[i][1][r] + bv[1];
                float v2 = acc[i][2][r] + bv[2];
                float v3 = acc[i][3][r] + bv[3];
                const size_t base = ((size_t)(b * H_ + h) * T_ + t) * HD_;
                if (region < 2) {
                    const float cz = rope[t * 32 + d * 2];
                    const float sz = rope[t * 32 + d * 2 + 1];
                    const float n0 = v0 * cz - v1 * sz;
                    const float n1 = v1 * cz + v0 * sz;
                    dst[base + d] = f2b(n0);
                    dst[base + 16 + d] = f2b(n1);
                } else {
                    dst[base + d] = f2b(v0);
                    dst[base + 16 + d] = f2b(v1);
                }
                dst[base + 32 + d] = f2b(v2);
                dst[base + 48 + d] = f2b(v3);
            }
        }
    } else {
        float* outf = (float*)o0v;
#pragma unroll
        for (int i = 0; i < 4; i++)
#pragma unroll
            for (int r = 0; r < 4; r++) {
                const int m = mBase + wr * 64 + i * 16 + quad * 4 + r;
                const size_t o = (size_t)m * 2048 + nq;
#pragma unroll
                for (int j = 0; j < 4; j++)
                    outf[o + j * 16 + l15] = acc[i][j][r] + bv[j];
            }
    }
}

// ---------------------------------------------------------------------------
// MFMA flash attention — round-7 verified structure (KVBLK=64, Vt[2] dbuf,
// lgkm-only barrier, balanced pairs {x,15-x}, T13 defer-max, single-buffer
// K-prefetch kC[8]) + ONE order-only delta (T14 stage-split, G15):
//  * Vt ds_write + lgkmcnt(0) + barrier moved from right-after-QK to
//    right-before-PV. Nothing between them touches Vt (softmax + Pt are
//    register / per-wave-LDS only), so the V-load vmcnt wait gains ~300+ cy
//    of cover (QK + mask/max + shfl + exp/pack) instead of ~80 cy (QK only).
//    The write's vmcnt wait is age-ordered: younger K-prefetch stays in
//    flight. ABA safety unchanged: one barrier/iter + double buffer means a
//    wave writes Vt[gb] at iter kt+2 only after passing barrier(kt+1), which
//    all waves reach only after finishing PV reads of Vt[gb] at iter kt.
//  * No setprio (round-8: negative in barrier-locked blocks). No V-register
//    prefetch (round-8 suspect). No launch-bounds pin (round-5 spill). No
//    wave decoupling (round-9: x4 V traffic + VMEM issue flood, -29 us).
// ---------------------------------------------------------------------------
#define VT_STR 72

#define LOADK(DST, KT)                                                         \
  {                                                                            \
    const u16* kp_ = kbase + (size_t)(KT) * 64 * HD_;                          \
    _Pragma("unroll") for (int mi = 0; mi < 4; mi++) {                         \
      const u16* kr_ = kp_ + (mi * 16 + l15) * HD_ + quad * 8;                 \
      DST[2 * mi]     = __builtin_bit_cast(bf16x8, *(const u16x8*)(kr_));      \
      DST[2 * mi + 1] = __builtin_bit_cast(bf16x8, *(const u16x8*)(kr_ + 32)); \
    }                                                                          \
  }

__global__ __launch_bounds__(256) void attn_mfma(const u16* __restrict__ qT,
                                                 const u16* __restrict__ kT,
                                                 const u16* __restrict__ vT,
                                                 u16* __restrict__ ctx) {
    __shared__ __align__(16) u16 Vt[2][64 * VT_STR];     // V^T: [hd][key], x2
    __shared__ __align__(16) u16 Pt[4 * 16 * VT_STR];    // per-wave P^T: [q][key]

    const int tid = threadIdx.x;
    const int w = tid >> 6, lane = tid & 63;
    const int quad = lane >> 4, l15 = lane & 15;
    const int bh = blockIdx.y;
    const size_t headBase = (size_t)bh * (T_ * HD_);

    u16* myPt = &Pt[w * 16 * VT_STR];
    const int vhd = tid & 63, vkb = tid >> 6;
    const float SC = 0.18033688011112042f;   // 0.125 * log2(e)
    const u16* kbase = kT + headBase;

    int gb = 0;                              // Vt buffer parity (global across tiles)
#pragma unroll 1
    for (int ti = 0; ti < 2; ti++) {
        const int qt = ti ? (15 - (int)blockIdx.x) : (int)blockIdx.x;
        const int qrow = w * 16 + l15;

        bf16x8 qf[2];
        {
            const u16* qr = qT + headBase + ((size_t)qt * 64 + qrow) * HD_ + quad * 8;
            qf[0] = __builtin_bit_cast(bf16x8, *(const u16x8*)(qr));
            qf[1] = __builtin_bit_cast(bf16x8, *(const u16x8*)(qr + 32));
        }

        float m_i = -1e30f, l_i = 0.f;
        floatx4 oacc[4] = {};

        bf16x8 kC[8];
        LOADK(kC, 0)

#pragma unroll 1
        for (int kt = 0; kt <= qt; kt++) {
            const u16* vp = vT + headBase + (size_t)kt * 64 * HD_;

            // V gather issues first: consumed only at the post-softmax Vt write
            u16 vreg[16];
#pragma unroll
            for (int c = 0; c < 16; c++)
                vreg[c] = vp[(vkb * 16 + c) * HD_ + vhd];

            floatx4 st[4] = {};
#pragma unroll
            for (int mi = 0; mi < 4; mi++) {
                st[mi] = __builtin_amdgcn_mfma_f32_16x16x32_bf16(kC[2 * mi], qf[0], st[mi], 0, 0, 0);
                st[mi] = __builtin_amdgcn_mfma_f32_16x16x32_bf16(kC[2 * mi + 1], qf[1], st[mi], 0, 0, 0);
            }

            // prefetch next K tile into the SAME registers (WAR after MFMA reads)
            if (kt < qt) LOADK(kC, kt + 1)

            float pmax = -1e30f;
#pragma unroll
            for (int mi = 0; mi < 4; mi++)
#pragma unroll
                for (int r = 0; r < 4; r++) {
                    float sv = st[mi][r] * SC;   // score in log2 domain
                    if (kt == qt && (mi * 16 + quad * 4 + r) > qrow) sv = -1e30f;
                    st[mi][r] = sv;
                    pmax = fmaxf(pmax, sv);
                }
            pmax = fmaxf(pmax, __shfl_xor(pmax, 16, 64));
            pmax = fmaxf(pmax, __shfl_xor(pmax, 32, 64));

            // T13 defer-max: skip rescale chain unless max grew by >11 (log2)
            if (!__all(pmax <= m_i + 11.0f)) {
                const float mnew = fmaxf(m_i, pmax);
                const float alpha = __builtin_amdgcn_exp2f(m_i - mnew);
                m_i = mnew;
                l_i *= alpha;
#pragma unroll
                for (int mi = 0; mi < 4; mi++) oacc[mi] *= alpha;
            }

            float psum = 0.f;
#pragma unroll
            for (int mi = 0; mi < 4; mi++) {
                float p[4];
#pragma unroll
                for (int r = 0; r < 4; r++) {
                    p[r] = __builtin_amdgcn_exp2f(st[mi][r] - m_i);
                    psum += p[r];
                }
                const u32x2 pk2 = {pack2(p[0], p[1]), pack2(p[2], p[3])};
                *(u32x2*)&myPt[l15 * VT_STR + mi * 16 + quad * 4] = pk2;
            }
            psum += __shfl_xor(psum, 16, 64);
            psum += __shfl_xor(psum, 32, 64);
            l_i += psum;

            // ---- T14 write-late: Vt staging lands here, right before PV ----
            // (vmcnt wait on vreg got QK+softmax as cover; K-prefetch younger,
            // stays in flight)
            u16* vt = Vt[gb];
#pragma unroll
            for (int c4 = 0; c4 < 4; c4++) {
                const u16x4 vv = {vreg[c4 * 4], vreg[c4 * 4 + 1], vreg[c4 * 4 + 2], vreg[c4 * 4 + 3]};
                *(u16x4*)&vt[vhd * VT_STR + vkb * 16 + c4 * 4] = vv;
            }
            LGKM0();                          // drain ds_writes (Vt + own Pt); K loads in flight
            __builtin_amdgcn_s_barrier();

            bf16x8 pf[2];
            pf[0] = __builtin_bit_cast(bf16x8, *(const u16x8*)&myPt[l15 * VT_STR + quad * 8]);
            pf[1] = __builtin_bit_cast(bf16x8, *(const u16x8*)&myPt[l15 * VT_STR + 32 + quad * 8]);
#pragma unroll
            for (int mi = 0; mi < 4; mi++) {
                const bf16x8 vf0 = __builtin_bit_cast(bf16x8, *(const u16x8*)&vt[(mi * 16 + l15) * VT_STR + quad * 8]);
                const bf16x8 vf1 = __builtin_bit_cast(bf16x8, *(const u16x8*)&vt[(mi * 16 + l15) * VT_STR + 32 + quad * 8]);
                oacc[mi] = __builtin_amdgcn_mfma_f32_16x16x32_bf16(vf0, pf[0], oacc[mi], 0, 0, 0);
                oacc[mi] = __builtin_amdgcn_mfma_f32_16x16x32_bf16(vf1, pf[1], oacc[mi], 0, 0, 0);
            }
            gb ^= 1;
        }

        const float inv = 1.0f / l_i;
        const int b = bh >> 5, h = bh & 31;
        const int t = qt * 64 + qrow;
        u16* cp = ctx + ((size_t)(b * T_ + t)) * C_ + h * HD_;
#pragma unroll
        for (int mi = 0; mi < 4; mi++) {
            const u16x4 ov = {f2b(oacc[mi][0] * inv), f2b(oacc[mi][1] * inv),
                              f2b(oacc[mi][2] * inv), f2b(oacc[mi][3] * inv)};
            *(u16x4*)(cp + mi * 16 + quad * 4) = ov;
        }
    }
}

extern "C" void kernel_launch(void* const* d_in, const int* in_sizes, int n_in,
                              void* d_out, int out_size, void* d_ws, size_t ws_size,
                              hipStream_t stream) {
    const float* x      = (const float*)d_in[0];
    const float* rope   = (const float*)d_in[3];
    const float* Wqkv_w = (const float*)d_in[4];
    const float* Wqkv_b = (const float*)d_in[5];
    const float* out_w  = (const float*)d_in[6];
    const float* out_b  = (const float*)d_in[7];
    float* out = (float*)d_out;

    // ws layout (u16 elems), total 100.7 MB:
    //   xb 8.39M | wqkvb 12.58M | outwb 4.19M | qT 8.39M | kT 8.39M | vT 8.39M
    //   xb|wqkvb|outwb contiguous (fused convert); ctx aliases xb (x dead after gemm0)
    const size_t headElems = (size_t)B_ * H_ * T_ * HD_;     // 8388608
    u16* xb    = (u16*)d_ws;
    u16* wqkvb = xb + headElems;
    u16* outwb = wqkvb + 12582912;
    u16* qTp   = outwb + 4194304;
    u16* kTp   = qTp + headElems;
    u16* vTp   = kTp + headElems;
    u16* ctx   = xb;

    convert_all<<<dim3(3072), 256, 0, stream>>>(x, Wqkv_w, out_w, xb);

    gemm_bt<0><<<dim3(48, 32), 256, 0, stream>>>(xb, wqkvb, Wqkv_b, rope, qTp, kTp, vTp);
    attn_mfma<<<dim3(8, 128), 256, 0, stream>>>(qTp, kTp, vTp, ctx);
    gemm_bt<1><<<dim3(16, 32), 256, 0, stream>>>(ctx, outwb, out_b, rope, out, nullptr, nullptr);
}

// Round 11
// 413.143 us; speedup vs baseline: 1.0833x; 1.0337x over previous
//
#include <hip/hip_runtime.h>

typedef unsigned short u16;
typedef unsigned int u32;
typedef __bf16 bf16x8 __attribute__((ext_vector_type(8)));
typedef float floatx4 __attribute__((ext_vector_type(4)));
typedef u16 u16x4 __attribute__((ext_vector_type(4)));
typedef u16 u16x8 __attribute__((ext_vector_type(8)));
typedef u32 u32x2 __attribute__((ext_vector_type(2)));

#define B_ 4
#define T_ 1024
#define C_ 2048
#define H_ 32
#define HD_ 64

__device__ __forceinline__ float b2f(u16 u) {
    u32 x = ((u32)u) << 16;
    return __builtin_bit_cast(float, x);
}
__device__ __forceinline__ u16 f2b(float f) {          // RNE (epilogues)
    u32 i = __builtin_bit_cast(u32, f);
    u32 r = (i + 0x7FFFu + ((i >> 16) & 1u)) >> 16;
    return (u16)r;
}
// pack two fp32 -> two bf16 (round-half-up), 2 adds + 1 v_perm_b32
__device__ __forceinline__ u32 pack2(float a, float b) {
    const u32 ua = __builtin_bit_cast(u32, a) + 0x8000u;
    const u32 ub = __builtin_bit_cast(u32, b) + 0x8000u;
    return __builtin_amdgcn_perm(ub, ua, 0x07060302u);  // [ub_hi : ua_hi]
}

#define GLOAD16(gp, lp) __builtin_amdgcn_global_load_lds( \
    (const __attribute__((address_space(1))) void*)(gp),  \
    (__attribute__((address_space(3))) void*)(lp), 16, 0, 0)

#define LGKM0() asm volatile("s_waitcnt lgkmcnt(0)" ::: "memory")

// ---------------------------------------------------------------------------
// fused fp32 -> bf16 convert for x | Wqkv_w | out_w (contiguous dst in ws).
// Verified round 4 (gemm counters unchanged; -2 launches).
// ---------------------------------------------------------------------------
__global__ __launch_bounds__(256) void convert_all(const float* __restrict__ x,
                                                   const float* __restrict__ wqkv,
                                                   const float* __restrict__ outw,
                                                   u16* __restrict__ dst) {
    const int stride = gridDim.x * 256;
    for (int i = blockIdx.x * 256 + threadIdx.x; i < 6291456; i += stride) {
        const float* s;
        int off;
        if (i < 2097152) { s = x; off = i; }
        else if (i < 5242880) { s = wqkv; off = i - 2097152; }
        else { s = outw; off = i - 5242880; }
        const floatx4 v = *(const floatx4*)(s + (size_t)off * 4);
        const u32x2 h = {pack2(v.x, v.y), pack2(v.z, v.w)};
        *(u32x2*)(dst + (size_t)i * 4) = h;
    }
}

// ---------------------------------------------------------------------------
// GEMM: C[m,n] = sum_k A[m,k] * W[n,k] + bias[n]   (A, W bf16 row-major)
// m97 structure + XOR-swizzled LDS. Verified 828 TF on the QKV shape.
// (256^2 8-phase measured SLOWER at this shape: 384 blocks at 1 block/CU ->
// 75% tail cap, resident MfmaUtil no better than 37%. Do not revisit.)
// MODE 0: epilogue bias + RoPE + scatter to q/k/v (B,H,T,hd) bf16.
// MODE 1: epilogue bias, fp32 row-major store.
// ---------------------------------------------------------------------------
template <int MODE>
__global__ __launch_bounds__(256) void gemm_bt(const u16* __restrict__ A,
                                               const u16* __restrict__ W,
                                               const float* __restrict__ bias,
                                               const float* __restrict__ rope,
                                               void* __restrict__ o0v,
                                               u16* __restrict__ o1,
                                               u16* __restrict__ o2) {
    const int Kdim = 2048;
    __shared__ __align__(16) u16 As[128 * 64];
    __shared__ __align__(16) u16 Bs[128 * 64];

    const int tid = threadIdx.x;
    const int w = tid >> 6, lane = tid & 63;
    const int wr = w >> 1, wc = w & 1;
    const int quad = lane >> 4, l15 = lane & 15;
    const int mBase = blockIdx.y * 128, nBase = blockIdx.x * 128;

    floatx4 acc[4][4] = {};

    // swizzled staging: local row lrow, fetch col-block (lane&7)^lrow
    const int lrow = lane >> 3;
    const int lcol = ((lane & 7) ^ lrow) * 8;
    const u16* Ap = A + (size_t)(mBase + lrow) * Kdim + lcol;
    const u16* Wp = W + (size_t)(nBase + lrow) * Kdim + lcol;

    const int xk = l15 & 7;   // read-side XOR key (row & 7)

    for (int k0 = 0; k0 < Kdim; k0 += 64) {
#pragma unroll
        for (int i = 0; i < 4; i++) {
            const int c = i * 4 + w;
            GLOAD16(Ap + (size_t)c * 8 * Kdim + k0, &As[c * 512]);
            GLOAD16(Wp + (size_t)c * 8 * Kdim + k0, &Bs[c * 512]);
        }
        __syncthreads();
#pragma unroll
        for (int ks = 0; ks < 64; ks += 32) {
            bf16x8 af[4], bfr[4];
#pragma unroll
            for (int i = 0; i < 4; i++) {
                const int co = (((ks >> 3) + quad) ^ xk) * 8;
                af[i] = *(const bf16x8*)&As[(wr * 64 + i * 16 + l15) * 64 + co];
            }
#pragma unroll
            for (int j = 0; j < 4; j++) {
                const int co = (((ks >> 3) + quad) ^ xk) * 8;
                bfr[j] = *(const bf16x8*)&Bs[(wc * 64 + j * 16 + l15) * 64 + co];
            }
#pragma unroll
            for (int i = 0; i < 4; i++)
#pragma unroll
                for (int j = 0; j < 4; j++)
                    acc[i][j] = __builtin_amdgcn_mfma_f32_16x16x32_bf16(af[i], bfr[j], acc[i][j], 0, 0, 0);
        }
        __syncthreads();
    }

    // epilogue: C/D layout col = lane&15 (per j-frag), row = quad*4 + reg (per i-frag)
    const int nq = nBase + wc * 64;
    float bv[4];
#pragma unroll
    for (int j = 0; j < 4; j++) bv[j] = bias[nq + j * 16 + l15];

    if (MODE == 0) {
        const int region = nq >> 11;            // 0=q 1=k 2=v (tile never straddles)
        const int h = (nq & 2047) >> 6;
        const int d = l15;
        u16* dst = (region == 0) ? (u16*)o0v : ((region == 1) ? o1 : o2);
#pragma unroll
        for (int i = 0; i < 4; i++) {
#pragma unroll
            for (int r = 0; r < 4; r++) {
                const int m = mBase + wr * 64 + i * 16 + quad * 4 + r;
                const int b = m >> 10, t = m & 1023;
                float v0 = acc[i][0][r] + bv[0];
                float v1 = acc[i][1][r] + bv[1];
                float v2 = acc[i][2][r] + bv[2];
                float v3 = acc[i][3][r] + bv[3];
                const size_t base = ((size_t)(b * H_ + h) * T_ + t) * HD_;
                if (region < 2) {
                    const float cz = rope[t * 32 + d * 2];
                    const float sz = rope[t * 32 + d * 2 + 1];
                    const float n0 = v0 * cz - v1 * sz;
                    const float n1 = v1 * cz + v0 * sz;
                    dst[base + d] = f2b(n0);
                    dst[base + 16 + d] = f2b(n1);
                } else {
                    dst[base + d] = f2b(v0);
                    dst[base + 16 + d] = f2b(v1);
                }
                dst[base + 32 + d] = f2b(v2);
                dst[base + 48 + d] = f2b(v3);
            }
        }
    } else {
        float* outf = (float*)o0v;
#pragma unroll
        for (int i = 0; i < 4; i++)
#pragma unroll
            for (int r = 0; r < 4; r++) {
                const int m = mBase + wr * 64 + i * 16 + quad * 4 + r;
                const size_t o = (size_t)m * 2048 + nq;
#pragma unroll
                for (int j = 0; j < 4; j++)
                    outf[o + j * 16 + l15] = acc[i][j][r] + bv[j];
            }
    }
}

// ---------------------------------------------------------------------------
// MFMA flash attention — round-7 verified schedule, UNTOUCHED (KVBLK=64,
// Vt[2] dbuf, barrier right after staging, lgkm-only drain, T13 defer-max,
// single-buffer K-prefetch kC[8]). Schedule is a measured local optimum:
// r8 (V-prefetch+setprio) -11us, r9 (wave-decoupled) -29us, r10 (write-late
// barrier) -8us. Do not reorder the iteration body.
// ONE mapping-only delta (T1, head-grouped XCD swizzle):
//   default lin=bh*8+pair -> xcd=lin%8=pair puts ALL 128 heads on every XCD
//   (32MB K/V through 4MB L2 -> thrash; attn FETCH was 120MB vs ~48 ideal).
//   Remap bijectively so xcd=head%8: each XCD hosts 16 heads x 8 pair-blocks,
//   K+V working set = 16 x 256KB = 4MB = one L2; each head's K/V fetched
//   once per XCD, re-read ~8.5x from L2. Worst case (mapping assumption
//   wrong): a bijective reorder, perf-neutral, correctness unaffected.
// ---------------------------------------------------------------------------
#define VT_STR 72

#define LOADK(DST, KT)                                                         \
  {                                                                            \
    const u16* kp_ = kbase + (size_t)(KT) * 64 * HD_;                          \
    _Pragma("unroll") for (int mi = 0; mi < 4; mi++) {                         \
      const u16* kr_ = kp_ + (mi * 16 + l15) * HD_ + quad * 8;                 \
      DST[2 * mi]     = __builtin_bit_cast(bf16x8, *(const u16x8*)(kr_));      \
      DST[2 * mi + 1] = __builtin_bit_cast(bf16x8, *(const u16x8*)(kr_ + 32)); \
    }                                                                          \
  }

__global__ __launch_bounds__(256) void attn_mfma(const u16* __restrict__ qT,
                                                 const u16* __restrict__ kT,
                                                 const u16* __restrict__ vT,
                                                 u16* __restrict__ ctx) {
    __shared__ __align__(16) u16 Vt[2][64 * VT_STR];     // V^T: [hd][key], x2
    __shared__ __align__(16) u16 Pt[4 * 16 * VT_STR];    // per-wave P^T: [q][key]

    const int tid = threadIdx.x;
    const int w = tid >> 6, lane = tid & 63;
    const int quad = lane >> 4, l15 = lane & 15;

    // T1 head-grouped XCD swizzle (bijective): lin -> (xcd, pair, head)
    const int lin = (int)blockIdx.y * 8 + (int)blockIdx.x;
    const int xcd = lin & 7;
    const int jj = lin >> 3;            // 0..127
    const int pair = jj >> 4;           // 0..7
    const int bh = (jj & 15) * 8 + xcd; // 0..127, head%8 == xcd

    const size_t headBase = (size_t)bh * (T_ * HD_);

    u16* myPt = &Pt[w * 16 * VT_STR];
    const int vhd = tid & 63, vkb = tid >> 6;
    const float SC = 0.18033688011112042f;   // 0.125 * log2(e)
    const u16* kbase = kT + headBase;

    int gb = 0;                              // Vt buffer parity (global across tiles)
#pragma unroll 1
    for (int ti = 0; ti < 2; ti++) {
        const int qt = ti ? (15 - pair) : pair;
        const int qrow = w * 16 + l15;

        bf16x8 qf[2];
        {
            const u16* qr = qT + headBase + ((size_t)qt * 64 + qrow) * HD_ + quad * 8;
            qf[0] = __builtin_bit_cast(bf16x8, *(const u16x8*)(qr));
            qf[1] = __builtin_bit_cast(bf16x8, *(const u16x8*)(qr + 32));
        }

        float m_i = -1e30f, l_i = 0.f;
        floatx4 oacc[4] = {};

        bf16x8 kC[8];
        LOADK(kC, 0)

#pragma unroll 1
        for (int kt = 0; kt <= qt; kt++) {
            const u16* vp = vT + headBase + (size_t)kt * 64 * HD_;

            u16 vreg[16];
#pragma unroll
            for (int c = 0; c < 16; c++)
                vreg[c] = vp[(vkb * 16 + c) * HD_ + vhd];

            floatx4 st[4] = {};
#pragma unroll
            for (int mi = 0; mi < 4; mi++) {
                st[mi] = __builtin_amdgcn_mfma_f32_16x16x32_bf16(kC[2 * mi], qf[0], st[mi], 0, 0, 0);
                st[mi] = __builtin_amdgcn_mfma_f32_16x16x32_bf16(kC[2 * mi + 1], qf[1], st[mi], 0, 0, 0);
            }

            // prefetch next K tile into the SAME registers (WAR after MFMA reads)
            if (kt < qt) LOADK(kC, kt + 1)

            // write V^T into current buffer; previous buffer is being read by
            // laggards of iteration kt-1 (same-buffer reuse is two barriers away)
            u16* vt = Vt[gb];
#pragma unroll
            for (int c4 = 0; c4 < 4; c4++) {
                const u16x4 vv = {vreg[c4 * 4], vreg[c4 * 4 + 1], vreg[c4 * 4 + 2], vreg[c4 * 4 + 3]};
                *(u16x4*)&vt[vhd * VT_STR + vkb * 16 + c4 * 4] = vv;
            }
            LGKM0();                          // drain ds_writes only (keep K loads in flight)
            __builtin_amdgcn_s_barrier();

            float pmax = -1e30f;
#pragma unroll
            for (int mi = 0; mi < 4; mi++)
#pragma unroll
                for (int r = 0; r < 4; r++) {
                    float sv = st[mi][r] * SC;   // score in log2 domain
                    if (kt == qt && (mi * 16 + quad * 4 + r) > qrow) sv = -1e30f;
                    st[mi][r] = sv;
                    pmax = fmaxf(pmax, sv);
                }
            pmax = fmaxf(pmax, __shfl_xor(pmax, 16, 64));
            pmax = fmaxf(pmax, __shfl_xor(pmax, 32, 64));

            // T13 defer-max: skip rescale chain unless max grew by >11 (log2)
            if (!__all(pmax <= m_i + 11.0f)) {
                const float mnew = fmaxf(m_i, pmax);
                const float alpha = __builtin_amdgcn_exp2f(m_i - mnew);
                m_i = mnew;
                l_i *= alpha;
#pragma unroll
                for (int mi = 0; mi < 4; mi++) oacc[mi] *= alpha;
            }

            float psum = 0.f;
#pragma unroll
            for (int mi = 0; mi < 4; mi++) {
                float p[4];
#pragma unroll
                for (int r = 0; r < 4; r++) {
                    p[r] = __builtin_amdgcn_exp2f(st[mi][r] - m_i);
                    psum += p[r];
                }
                const u32x2 pk2 = {pack2(p[0], p[1]), pack2(p[2], p[3])};
                *(u32x2*)&myPt[l15 * VT_STR + mi * 16 + quad * 4] = pk2;
            }
            psum += __shfl_xor(psum, 16, 64);
            psum += __shfl_xor(psum, 32, 64);
            l_i += psum;

            bf16x8 pf[2];
            pf[0] = __builtin_bit_cast(bf16x8, *(const u16x8*)&myPt[l15 * VT_STR + quad * 8]);
            pf[1] = __builtin_bit_cast(bf16x8, *(const u16x8*)&myPt[l15 * VT_STR + 32 + quad * 8]);
#pragma unroll
            for (int mi = 0; mi < 4; mi++) {
                const bf16x8 vf0 = __builtin_bit_cast(bf16x8, *(const u16x8*)&vt[(mi * 16 + l15) * VT_STR + quad * 8]);
                const bf16x8 vf1 = __builtin_bit_cast(bf16x8, *(const u16x8*)&vt[(mi * 16 + l15) * VT_STR + 32 + quad * 8]);
                oacc[mi] = __builtin_amdgcn_mfma_f32_16x16x32_bf16(vf0, pf[0], oacc[mi], 0, 0, 0);
                oacc[mi] = __builtin_amdgcn_mfma_f32_16x16x32_bf16(vf1, pf[1], oacc[mi], 0, 0, 0);
            }
            gb ^= 1;
        }

        const float inv = 1.0f / l_i;
        const int b = bh >> 5, h = bh & 31;
        const int t = qt * 64 + qrow;
        u16* cp = ctx + ((size_t)(b * T_ + t)) * C_ + h * HD_;
#pragma unroll
        for (int mi = 0; mi < 4; mi++) {
            const u16x4 ov = {f2b(oacc[mi][0] * inv), f2b(oacc[mi][1] * inv),
                              f2b(oacc[mi][2] * inv), f2b(oacc[mi][3] * inv)};
            *(u16x4*)(cp + mi * 16 + quad * 4) = ov;
        }
    }
}

extern "C" void kernel_launch(void* const* d_in, const int* in_sizes, int n_in,
                              void* d_out, int out_size, void* d_ws, size_t ws_size,
                              hipStream_t stream) {
    const float* x      = (const float*)d_in[0];
    const float* rope   = (const float*)d_in[3];
    const float* Wqkv_w = (const float*)d_in[4];
    const float* Wqkv_b = (const float*)d_in[5];
    const float* out_w  = (const float*)d_in[6];
    const float* out_b  = (const float*)d_in[7];
    float* out = (float*)d_out;

    // ws layout (u16 elems), total 100.7 MB:
    //   xb 8.39M | wqkvb 12.58M | outwb 4.19M | qT 8.39M | kT 8.39M | vT 8.39M
    //   xb|wqkvb|outwb contiguous (fused convert); ctx aliases xb (x dead after gemm0)
    const size_t headElems = (size_t)B_ * H_ * T_ * HD_;     // 8388608
    u16* xb    = (u16*)d_ws;
    u16* wqkvb = xb + headElems;
    u16* outwb = wqkvb + 12582912;
    u16* qTp   = outwb + 4194304;
    u16* kTp   = qTp + headElems;
    u16* vTp   = kTp + headElems;
    u16* ctx   = xb;

    convert_all<<<dim3(3072), 256, 0, stream>>>(x, Wqkv_w, out_w, xb);

    gemm_bt<0><<<dim3(48, 32), 256, 0, stream>>>(xb, wqkvb, Wqkv_b, rope, qTp, kTp, vTp);
    attn_mfma<<<dim3(8, 128), 256, 0, stream>>>(qTp, kTp, vTp, ctx);
    gemm_bt<1><<<dim3(16, 32), 256, 0, stream>>>(ctx, outwb, out_b, rope, out, nullptr, nullptr);
}

// Round 12
// 407.013 us; speedup vs baseline: 1.0996x; 1.0151x over previous
//
#include <hip/hip_runtime.h>

typedef unsigned short u16;
typedef unsigned int u32;
typedef __bf16 bf16x8 __attribute__((ext_vector_type(8)));
typedef float floatx4 __attribute__((ext_vector_type(4)));
typedef u16 u16x4 __attribute__((ext_vector_type(4)));
typedef u16 u16x8 __attribute__((ext_vector_type(8)));
typedef u32 u32x2 __attribute__((ext_vector_type(2)));

#define B_ 4
#define T_ 1024
#define C_ 2048
#define H_ 32
#define HD_ 64

__device__ __forceinline__ float b2f(u16 u) {
    u32 x = ((u32)u) << 16;
    return __builtin_bit_cast(float, x);
}
__device__ __forceinline__ u16 f2b(float f) {          // RNE (epilogues)
    u32 i = __builtin_bit_cast(u32, f);
    u32 r = (i + 0x7FFFu + ((i >> 16) & 1u)) >> 16;
    return (u16)r;
}
// pack two fp32 -> two bf16 (round-half-up), 2 adds + 1 v_perm_b32
__device__ __forceinline__ u32 pack2(float a, float b) {
    const u32 ua = __builtin_bit_cast(u32, a) + 0x8000u;
    const u32 ub = __builtin_bit_cast(u32, b) + 0x8000u;
    return __builtin_amdgcn_perm(ub, ua, 0x07060302u);  // [ub_hi : ua_hi]
}

#define GLOAD16(gp, lp) __builtin_amdgcn_global_load_lds( \
    (const __attribute__((address_space(1))) void*)(gp),  \
    (__attribute__((address_space(3))) void*)(lp), 16, 0, 0)

#define LGKM0() asm volatile("s_waitcnt lgkmcnt(0)" ::: "memory")

// ---------------------------------------------------------------------------
// fused fp32 -> bf16 convert for x | Wqkv_w | out_w (contiguous dst in ws).
// Verified round 4 (gemm counters unchanged; -2 launches).
// ---------------------------------------------------------------------------
__global__ __launch_bounds__(256) void convert_all(const float* __restrict__ x,
                                                   const float* __restrict__ wqkv,
                                                   const float* __restrict__ outw,
                                                   u16* __restrict__ dst) {
    const int stride = gridDim.x * 256;
    for (int i = blockIdx.x * 256 + threadIdx.x; i < 6291456; i += stride) {
        const float* s;
        int off;
        if (i < 2097152) { s = x; off = i; }
        else if (i < 5242880) { s = wqkv; off = i - 2097152; }
        else { s = outw; off = i - 5242880; }
        const floatx4 v = *(const floatx4*)(s + (size_t)off * 4);
        const u32x2 h = {pack2(v.x, v.y), pack2(v.z, v.w)};
        *(u32x2*)(dst + (size_t)i * 4) = h;
    }
}

// ---------------------------------------------------------------------------
// GEMM: C[m,n] = sum_k A[m,k] * W[n,k] + bias[n]   (A, W bf16 row-major)
// m97 structure + XOR-swizzled LDS. Verified 828 TF on the QKV shape.
// (256^2 8-phase measured SLOWER at this shape: 384 blocks at 1 block/CU ->
// 75% tail cap, resident MfmaUtil no better than 37%. Do not revisit.)
// MODE 0: epilogue bias + RoPE + scatter to q/k/v (B,H,T,hd) bf16.
// MODE 1: epilogue bias, fp32 row-major store.
// ---------------------------------------------------------------------------
template <int MODE>
__global__ __launch_bounds__(256) void gemm_bt(const u16* __restrict__ A,
                                               const u16* __restrict__ W,
                                               const float* __restrict__ bias,
                                               const float* __restrict__ rope,
                                               void* __restrict__ o0v,
                                               u16* __restrict__ o1,
                                               u16* __restrict__ o2) {
    const int Kdim = 2048;
    __shared__ __align__(16) u16 As[128 * 64];
    __shared__ __align__(16) u16 Bs[128 * 64];

    const int tid = threadIdx.x;
    const int w = tid >> 6, lane = tid & 63;
    const int wr = w >> 1, wc = w & 1;
    const int quad = lane >> 4, l15 = lane & 15;
    const int mBase = blockIdx.y * 128, nBase = blockIdx.x * 128;

    floatx4 acc[4][4] = {};

    // swizzled staging: local row lrow, fetch col-block (lane&7)^lrow
    const int lrow = lane >> 3;
    const int lcol = ((lane & 7) ^ lrow) * 8;
    const u16* Ap = A + (size_t)(mBase + lrow) * Kdim + lcol;
    const u16* Wp = W + (size_t)(nBase + lrow) * Kdim + lcol;

    const int xk = l15 & 7;   // read-side XOR key (row & 7)

    for (int k0 = 0; k0 < Kdim; k0 += 64) {
#pragma unroll
        for (int i = 0; i < 4; i++) {
            const int c = i * 4 + w;
            GLOAD16(Ap + (size_t)c * 8 * Kdim + k0, &As[c * 512]);
            GLOAD16(Wp + (size_t)c * 8 * Kdim + k0, &Bs[c * 512]);
        }
        __syncthreads();
#pragma unroll
        for (int ks = 0; ks < 64; ks += 32) {
            bf16x8 af[4], bfr[4];
#pragma unroll
            for (int i = 0; i < 4; i++) {
                const int co = (((ks >> 3) + quad) ^ xk) * 8;
                af[i] = *(const bf16x8*)&As[(wr * 64 + i * 16 + l15) * 64 + co];
            }
#pragma unroll
            for (int j = 0; j < 4; j++) {
                const int co = (((ks >> 3) + quad) ^ xk) * 8;
                bfr[j] = *(const bf16x8*)&Bs[(wc * 64 + j * 16 + l15) * 64 + co];
            }
#pragma unroll
            for (int i = 0; i < 4; i++)
#pragma unroll
                for (int j = 0; j < 4; j++)
                    acc[i][j] = __builtin_amdgcn_mfma_f32_16x16x32_bf16(af[i], bfr[j], acc[i][j], 0, 0, 0);
        }
        __syncthreads();
    }

    // epilogue: C/D layout col = lane&15 (per j-frag), row = quad*4 + reg (per i-frag)
    const int nq = nBase + wc * 64;
    float bv[4];
#pragma unroll
    for (int j = 0; j < 4; j++) bv[j] = bias[nq + j * 16 + l15];

    if (MODE == 0) {
        const int region = nq >> 11;            // 0=q 1=k 2=v (tile never straddles)
        const int h = (nq & 2047) >> 6;
        const int d = l15;
        u16* dst = (region == 0) ? (u16*)o0v : ((region == 1) ? o1 : o2);
#pragma unroll
        for (int i = 0; i < 4; i++) {
#pragma unroll
            for (int r = 0; r < 4; r++) {
                const int m = mBase + wr * 64 + i * 16 + quad * 4 + r;
                const int b = m >> 10, t = m & 1023;
                float v0 = acc[i][0][r] + bv[0];
                float v1 = acc[i][1][r] + bv[1];
                float v2 = acc[i][2][r] + bv[2];
                float v3 = acc[i][3][r] + bv[3];
                const size_t base = ((size_t)(b * H_ + h) * T_ + t) * HD_;
                if (region < 2) {
                    const float cz = rope[t * 32 + d * 2];
                    const float sz = rope[t * 32 + d * 2 + 1];
                    const float n0 = v0 * cz - v1 * sz;
                    const float n1 = v1 * cz + v0 * sz;
                    dst[base + d] = f2b(n0);
                    dst[base + 16 + d] = f2b(n1);
                } else {
                    dst[base + d] = f2b(v0);
                    dst[base + 16 + d] = f2b(v1);
                }
                dst[base + 32 + d] = f2b(v2);
                dst[base + 48 + d] = f2b(v3);
            }
        }
    } else {
        float* outf = (float*)o0v;
#pragma unroll
        for (int i = 0; i < 4; i++)
#pragma unroll
            for (int r = 0; r < 4; r++) {
                const int m = mBase + wr * 64 + i * 16 + quad * 4 + r;
                const size_t o = (size_t)m * 2048 + nq;
#pragma unroll
                for (int j = 0; j < 4; j++)
                    outf[o + j * 16 + l15] = acc[i][j][r] + bv[j];
            }
    }
}

// ---------------------------------------------------------------------------
// MFMA flash attention — FUSED balanced pair (round 12).
// The pair {x, 15-x} is processed in ONE pass over K/V tiles 0..15-x: for
// kt <= x BOTH q-tiles consume the same K registers and same Vt staging, so
// one V-gather + one K-load + one Vt-write + one barrier serve 2x the
// MFMA/softmax. Per block this deletes (x+1) staging+barrier units
// (17 -> 16-x units; per-CU 68 -> 52/60, -24% of the latency-dominant work).
// Per-tile math is bitwise identical to r11 (same K order, same defer-max
// sequence) -> absmax must not move.
// Per-unit schedule order preserved from the r7/r11 verified optimum:
//   Vgather -> QK-A -> smA(->Pt) -> QK-B -> Kpre -> Vtwrite -> lgkm -> bar
//   -> PV-A (reads Pt BEFORE smB overwrites; same-wave DS ops are in program
//   order) -> smB(->Pt) -> PV-B.
// Single Pt region (LDS stays 27.6 KB); doA is wave-uniform (barrier-safe).
// K-prefetch kC[8] (r7), T13 defer-max (r6), T1 head-XCD swizzle (r11) kept.
// No setprio (r8), no wave-decoupling (r9), no write-late barrier (r10),
// no launch-bounds pin (r5). Tripwire: regression or absmax shift => revert.
// ---------------------------------------------------------------------------
#define VT_STR 72

#define LOADK(DST, KT)                                                         \
  {                                                                            \
    const u16* kp_ = kbase + (size_t)(KT) * 64 * HD_;                          \
    _Pragma("unroll") for (int mi = 0; mi < 4; mi++) {                         \
      const u16* kr_ = kp_ + (mi * 16 + l15) * HD_ + quad * 8;                 \
      DST[2 * mi]     = __builtin_bit_cast(bf16x8, *(const u16x8*)(kr_));      \
      DST[2 * mi + 1] = __builtin_bit_cast(bf16x8, *(const u16x8*)(kr_ + 32)); \
    }                                                                          \
  }

#define QKC(ST, QF)                                                            \
  _Pragma("unroll") for (int mi = 0; mi < 4; mi++) {                           \
    ST[mi] = floatx4{};                                                        \
    ST[mi] = __builtin_amdgcn_mfma_f32_16x16x32_bf16(kC[2 * mi], QF[0], ST[mi], 0, 0, 0);     \
    ST[mi] = __builtin_amdgcn_mfma_f32_16x16x32_bf16(kC[2 * mi + 1], QF[1], ST[mi], 0, 0, 0); \
  }

#define SMAXW(ST, M_I, L_I, OACC, QT)                                          \
  {                                                                            \
    float pmax_ = -1e30f;                                                      \
    const int diag_ = (kt == (QT));                                            \
    _Pragma("unroll") for (int mi = 0; mi < 4; mi++)                           \
      _Pragma("unroll") for (int r = 0; r < 4; r++) {                          \
        float sv = ST[mi][r] * SC;                                             \
        if (diag_ && (mi * 16 + quad * 4 + r) > qrow) sv = -1e30f;             \
        ST[mi][r] = sv;                                                        \
        pmax_ = fmaxf(pmax_, sv);                                              \
      }                                                                        \
    pmax_ = fmaxf(pmax_, __shfl_xor(pmax_, 16, 64));                           \
    pmax_ = fmaxf(pmax_, __shfl_xor(pmax_, 32, 64));                           \
    if (!__all(pmax_ <= M_I + 11.0f)) {                                        \
      const float mnew_ = fmaxf(M_I, pmax_);                                   \
      const float alpha_ = __builtin_amdgcn_exp2f(M_I - mnew_);                \
      M_I = mnew_;                                                             \
      L_I *= alpha_;                                                           \
      _Pragma("unroll") for (int mi = 0; mi < 4; mi++) OACC[mi] *= alpha_;     \
    }                                                                          \
    float psum_ = 0.f;                                                         \
    _Pragma("unroll") for (int mi = 0; mi < 4; mi++) {                         \
      float p0 = __builtin_amdgcn_exp2f(ST[mi][0] - M_I);                      \
      float p1 = __builtin_amdgcn_exp2f(ST[mi][1] - M_I);                      \
      float p2 = __builtin_amdgcn_exp2f(ST[mi][2] - M_I);                      \
      float p3 = __builtin_amdgcn_exp2f(ST[mi][3] - M_I);                      \
      psum_ += p0 + p1 + p2 + p3;                                              \
      const u32x2 pk2_ = {pack2(p0, p1), pack2(p2, p3)};                       \
      *(u32x2*)&myPt[l15 * VT_STR + mi * 16 + quad * 4] = pk2_;                \
    }                                                                          \
    psum_ += __shfl_xor(psum_, 16, 64);                                        \
    psum_ += __shfl_xor(psum_, 32, 64);                                        \
    L_I += psum_;                                                              \
  }

#define PVACC(OACC, VTP)                                                       \
  {                                                                            \
    const bf16x8 pf0_ = __builtin_bit_cast(bf16x8, *(const u16x8*)&myPt[l15 * VT_STR + quad * 8]);      \
    const bf16x8 pf1_ = __builtin_bit_cast(bf16x8, *(const u16x8*)&myPt[l15 * VT_STR + 32 + quad * 8]); \
    _Pragma("unroll") for (int mi = 0; mi < 4; mi++) {                         \
      const bf16x8 vf0_ = __builtin_bit_cast(bf16x8, *(const u16x8*)&(VTP)[(mi * 16 + l15) * VT_STR + quad * 8]);      \
      const bf16x8 vf1_ = __builtin_bit_cast(bf16x8, *(const u16x8*)&(VTP)[(mi * 16 + l15) * VT_STR + 32 + quad * 8]); \
      OACC[mi] = __builtin_amdgcn_mfma_f32_16x16x32_bf16(vf0_, pf0_, OACC[mi], 0, 0, 0);                \
      OACC[mi] = __builtin_amdgcn_mfma_f32_16x16x32_bf16(vf1_, pf1_, OACC[mi], 0, 0, 0);                \
    }                                                                          \
  }

#define STOREO(OACC, L_I, QT)                                                  \
  {                                                                            \
    const float inv_ = 1.0f / (L_I);                                           \
    const int t_ = (QT) * 64 + qrow;                                           \
    u16* cp_ = ctx + ((size_t)(bb * T_ + t_)) * C_ + hh * HD_;                 \
    _Pragma("unroll") for (int mi = 0; mi < 4; mi++) {                         \
      const u16x4 ov_ = {f2b(OACC[mi][0] * inv_), f2b(OACC[mi][1] * inv_),     \
                         f2b(OACC[mi][2] * inv_), f2b(OACC[mi][3] * inv_)};    \
      *(u16x4*)(cp_ + mi * 16 + quad * 4) = ov_;                               \
    }                                                                          \
  }

__global__ __launch_bounds__(256) void attn_mfma(const u16* __restrict__ qT,
                                                 const u16* __restrict__ kT,
                                                 const u16* __restrict__ vT,
                                                 u16* __restrict__ ctx) {
    __shared__ __align__(16) u16 Vt[2][64 * VT_STR];     // V^T: [hd][key], x2
    __shared__ __align__(16) u16 Pt[4 * 16 * VT_STR];    // per-wave P^T: [q][key]

    const int tid = threadIdx.x;
    const int w = tid >> 6, lane = tid & 63;
    const int quad = lane >> 4, l15 = lane & 15;

    // T1 head-grouped XCD swizzle (bijective): lin -> (xcd, pair, head)
    const int lin = (int)blockIdx.y * 8 + (int)blockIdx.x;
    const int xcd = lin & 7;
    const int jj = lin >> 3;            // 0..127
    const int pair = jj >> 4;           // 0..7
    const int bh = (jj & 15) * 8 + xcd; // 0..127, head%8 == xcd

    const size_t headBase = (size_t)bh * (T_ * HD_);
    const int bb = bh >> 5, hh = bh & 31;

    u16* myPt = &Pt[w * 16 * VT_STR];
    const int vhd = tid & 63, vkb = tid >> 6;
    const float SC = 0.18033688011112042f;   // 0.125 * log2(e)
    const u16* kbase = kT + headBase;
    const int qrow = w * 16 + l15;

    const int qtA = pair;                // small q-tile
    const int qtB = 15 - pair;           // large q-tile

    bf16x8 qfA[2], qfB[2];
    {
        const u16* qrA = qT + headBase + ((size_t)qtA * 64 + qrow) * HD_ + quad * 8;
        qfA[0] = __builtin_bit_cast(bf16x8, *(const u16x8*)(qrA));
        qfA[1] = __builtin_bit_cast(bf16x8, *(const u16x8*)(qrA + 32));
        const u16* qrB = qT + headBase + ((size_t)qtB * 64 + qrow) * HD_ + quad * 8;
        qfB[0] = __builtin_bit_cast(bf16x8, *(const u16x8*)(qrB));
        qfB[1] = __builtin_bit_cast(bf16x8, *(const u16x8*)(qrB + 32));
    }

    float mA = -1e30f, lA = 0.f, mB = -1e30f, lB = 0.f;
    floatx4 oaccA[4] = {}, oaccB[4] = {};

    bf16x8 kC[8];
    LOADK(kC, 0)

    int gb = 0;
#pragma unroll 1
    for (int kt = 0; kt <= qtB; kt++) {
        const int doA = (kt <= qtA);     // wave-uniform (barrier-safe)
        const u16* vp = vT + headBase + (size_t)kt * 64 * HD_;

        u16 vreg[16];
#pragma unroll
        for (int c = 0; c < 16; c++)
            vreg[c] = vp[(vkb * 16 + c) * HD_ + vhd];

        floatx4 st[4];
        if (doA) {
            QKC(st, qfA)
            SMAXW(st, mA, lA, oaccA, qtA)     // Pt <- P_A (pre-barrier)
        }
        QKC(st, qfB)                          // st reused after smA consumed it

        // prefetch next K tile into the SAME registers (WAR after MFMA reads)
        if (kt < qtB) LOADK(kC, kt + 1)

        // write V^T into current buffer; same ABA argument as r7/r11 (one
        // barrier/iter + double buffer: reuse is two barriers away)
        u16* vt = Vt[gb];
#pragma unroll
        for (int c4 = 0; c4 < 4; c4++) {
            const u16x4 vv = {vreg[c4 * 4], vreg[c4 * 4 + 1], vreg[c4 * 4 + 2], vreg[c4 * 4 + 3]};
            *(u16x4*)&vt[vhd * VT_STR + vkb * 16 + c4 * 4] = vv;
        }
        LGKM0();                          // drain ds_writes only (K loads stay in flight)
        __builtin_amdgcn_s_barrier();

        if (doA) { PVACC(oaccA, vt) }     // reads Pt(A) before smB overwrites it

        SMAXW(st, mB, lB, oaccB, qtB)     // Pt <- P_B (after PV-A's reads, program order)
        PVACC(oaccB, vt)
        gb ^= 1;
    }

    STOREO(oaccA, lA, qtA)
    STOREO(oaccB, lB, qtB)
}

extern "C" void kernel_launch(void* const* d_in, const int* in_sizes, int n_in,
                              void* d_out, int out_size, void* d_ws, size_t ws_size,
                              hipStream_t stream) {
    const float* x      = (const float*)d_in[0];
    const float* rope   = (const float*)d_in[3];
    const float* Wqkv_w = (const float*)d_in[4];
    const float* Wqkv_b = (const float*)d_in[5];
    const float* out_w  = (const float*)d_in[6];
    const float* out_b  = (const float*)d_in[7];
    float* out = (float*)d_out;

    // ws layout (u16 elems), total 100.7 MB:
    //   xb 8.39M | wqkvb 12.58M | outwb 4.19M | qT 8.39M | kT 8.39M | vT 8.39M
    //   xb|wqkvb|outwb contiguous (fused convert); ctx aliases xb (x dead after gemm0)
    const size_t headElems = (size_t)B_ * H_ * T_ * HD_;     // 8388608
    u16* xb    = (u16*)d_ws;
    u16* wqkvb = xb + headElems;
    u16* outwb = wqkvb + 12582912;
    u16* qTp   = outwb + 4194304;
    u16* kTp   = qTp + headElems;
    u16* vTp   = kTp + headElems;
    u16* ctx   = xb;

    convert_all<<<dim3(3072), 256, 0, stream>>>(x, Wqkv_w, out_w, xb);

    gemm_bt<0><<<dim3(48, 32), 256, 0, stream>>>(xb, wqkvb, Wqkv_b, rope, qTp, kTp, vTp);
    attn_mfma<<<dim3(8, 128), 256, 0, stream>>>(qTp, kTp, vTp, ctx);
    gemm_bt<1><<<dim3(16, 32), 256, 0, stream>>>(ctx, outwb, out_b, rope, out, nullptr, nullptr);
}